// Round 10
// baseline (171.864 us; speedup 1.0000x reference)
//
#include <hip/hip_runtime.h>
#include <math.h>

#define EPS 1e-5f
#define FLT_BIG 3.402823466e38f

typedef __attribute__((ext_vector_type(8))) short bf16x8;
typedef __attribute__((ext_vector_type(4))) float f32x4;

__device__ __forceinline__ unsigned fflip(float f){
  int i = __float_as_int(f);
  return (unsigned)(i ^ ((i>>31) | 0x80000000));
}
__device__ __forceinline__ float funflip(unsigned u){
  int i = (u & 0x80000000u) ? (int)(u ^ 0x80000000u) : (int)(~u);
  return __int_as_float(i);
}
__device__ __forceinline__ unsigned f2bf(float f){
  unsigned u = __float_as_uint(f);
  return (u + 0x7FFFu + ((u>>16)&1u)) >> 16;
}
__device__ __forceinline__ float bf_lo(unsigned v){ return __uint_as_float(v<<16); }
__device__ __forceinline__ float bf_hi(unsigned v){ return __uint_as_float(v & 0xFFFF0000u); }

__device__ __forceinline__ int lbound(const int* __restrict__ a, int n, int key){
  int lo=0, hi=n;
  while(lo<hi){ int mid=(lo+hi)>>1; if(a[mid]<key) lo=mid+1; else hi=mid; }
  return lo;
}

// ---- K1: multisplit bucketize (per-wave hist) + folded init side-work ----
// Record = (b<<24)|(dlow<<16)|src. Tile = 2048 edges/block.
// Blocks 0-7 pack W into B-frag order; block 8 computes gcnt + gblk.
__global__ __launch_bounds__(256) void k_bucketize(
    const int* __restrict__ src, const int* __restrict__ dst, int E, int NB,
    unsigned* __restrict__ gcur, unsigned* __restrict__ dstream,
    const float* __restrict__ Wg, ushort* __restrict__ Wp,
    const int* __restrict__ batch, int N, int* __restrict__ gcnt,
    int* __restrict__ gblk, int G){
  __shared__ unsigned whist[4][160];   // per-wave counts, then per-wave excl bases
  __shared__ unsigned hist[160];       // per-bucket totals
  __shared__ unsigned excl[160];
  __shared__ unsigned base[160];
  __shared__ unsigned wsum[4];
  __shared__ unsigned lsorted[2048];
  int t = threadIdx.x, bid = blockIdx.x;
  int wid = t>>6, lane = t&63;

  // ---- folded init side-work (independent of edge path) ----
  if(bid < 8){
    int i = bid*256 + t;                 // 0..2047
    int tile = i>>6, l = i&63;
    int kt = tile>>3, ct = tile&7;
    int q = l>>4, nn = l&15;
    ushort w8[8];
    #pragma unroll
    for(int j=0;j<8;j++)
      w8[j] = (ushort)f2bf(Wg[(kt*32 + q*8 + j)*128 + ct*16 + nn]);
    ushort* dstp = Wp + (size_t)i*8;
    #pragma unroll
    for(int j=0;j<8;j++) dstp[j] = w8[j];
  } else if(bid == 8){
    if(t < G){
      int s = lbound(batch,N,t), e = lbound(batch,N,t+1);
      gcnt[t] = e - s;
      gblk[t] = (e > s) ? (((e-1)>>6) - (s>>6) + 1) : 0;
    }
  }

  // ---- edge path ----
  int e0 = bid*2048 + t*8;
  unsigned rec[8]; int bk[8]; unsigned rr[8];
  #pragma unroll
  for(int j=0;j<8;j++) bk[j] = -1;
  if(e0+7 < E){
    int4 s0 = *(const int4*)(src+e0), s1 = *(const int4*)(src+e0+4);
    int4 d0 = *(const int4*)(dst+e0), d1 = *(const int4*)(dst+e0+4);
    int ss[8] = {s0.x,s0.y,s0.z,s0.w,s1.x,s1.y,s1.z,s1.w};
    int dd[8] = {d0.x,d0.y,d0.z,d0.w,d1.x,d1.y,d1.z,d1.w};
    #pragma unroll
    for(int j=0;j<8;j++){
      bk[j] = dd[j]>>8;
      rec[j] = ((unsigned)bk[j]<<24) | ((unsigned)(dd[j]&255)<<16) | (unsigned)ss[j];
    }
  } else {
    #pragma unroll
    for(int j=0;j<8;j++){
      int ee = e0+j;
      if(ee<E){
        int s = src[ee], d = dst[ee];
        bk[j] = d>>8;
        rec[j] = ((unsigned)bk[j]<<24) | ((unsigned)(d&255)<<16) | (unsigned)s;
      }
    }
  }
  for(int i=t;i<NB;i+=256){
    whist[0][i]=0u; whist[1][i]=0u; whist[2][i]=0u; whist[3][i]=0u;
  }
  __syncthreads();
  #pragma unroll
  for(int j=0;j<8;j++)
    if(bk[j]>=0) rr[j] = atomicAdd(&whist[wid][bk[j]],1u);
  __syncthreads();
  // per-bucket totals + per-wave exclusive bases
  unsigned hv = 0u;
  if(t<NB){
    unsigned h0=whist[0][t], h1=whist[1][t], h2=whist[2][t], h3=whist[3][t];
    hv = h0+h1+h2+h3;
    hist[t] = hv;
    whist[0][t]=0u; whist[1][t]=h0; whist[2][t]=h0+h1; whist[3][t]=h0+h1+h2;
  }
  // exclusive scan of hv via wave shfl scans + 1 barrier
  unsigned v = hv;
  #pragma unroll
  for(int d=1; d<64; d<<=1){
    unsigned o = __shfl_up(v, d, 64);
    if(lane >= d) v += o;
  }
  if(lane==63) wsum[wid] = v;
  __syncthreads();
  {
    unsigned pre = 0;
    if(wid>0) pre += wsum[0];
    if(wid>1) pre += wsum[1];
    if(wid>2) pre += wsum[2];
    if(t<NB) excl[t] = v + pre - hv;
  }
  if(t<NB){
    int ridx = t + bid; while(ridx>=NB) ridx-=NB;  // stagger global atomics
    base[ridx] = atomicAdd(&gcur[ridx], hist[ridx]);
  }
  __syncthreads();
  #pragma unroll
  for(int j=0;j<8;j++)
    if(bk[j]>=0) lsorted[excl[bk[j]] + whist[wid][bk[j]] + rr[j]] = rec[j];
  __syncthreads();
  int vc = E - bid*2048; if(vc>2048) vc=2048;
  #pragma unroll
  for(int j=0;j<8;j++){
    int k = j*256 + t;
    if(k<vc){
      unsigned rc = lsorted[k];
      unsigned bb = rc>>24;
      unsigned pos = base[bb] + (unsigned)k - excl[bb];
      if(pos < 8192u) dstream[((size_t)bb<<13) + pos] = rc;
    }
  }
}

// ---- K2: per-bucket CSR build in LDS (sentinel-padded) + writeout + fused dinv-scale ----
__global__ __launch_bounds__(1024) void k_csrscale(
    const unsigned* __restrict__ dstream, const unsigned* __restrict__ gcur,
    int N, ushort* __restrict__ csr, int* __restrict__ cursor,
    const float4* __restrict__ x4, uint2* __restrict__ xs2){
  __shared__ unsigned cnt[256];
  __shared__ float dv[256];
  __shared__ ushort slab[16384];       // 256 nodes x 64 slots = 2048 uint4
  int b = blockIdx.x, t = threadIdx.x;
  if(t<256) cnt[t]=0u;
  {
    unsigned sv = ((unsigned)N<<16) | (unsigned)N;   // sentinel bf pair
    uint4 fillv = make_uint4(sv,sv,sv,sv);
    #pragma unroll
    for(int i=t;i<2048;i+=1024) ((uint4*)slab)[i] = fillv;  // ALL 32768 B
  }
  // zero row N of xs (sentinel target), once
  if(b==0 && t<16) ((uint4*)(xs2 + ((size_t)N<<5)))[t] = make_uint4(0,0,0,0);
  __syncthreads();
  int nb = (int)gcur[b]; if(nb>8192) nb=8192;
  const unsigned* sp = dstream + ((size_t)b<<13);
  for(int i=t;i<nb;i+=1024){
    unsigned rc = sp[i];
    int dl = (rc>>16)&255;
    unsigned p = atomicAdd(&cnt[dl],1u);
    if(p<64u) slab[(dl<<6)+(int)p] = (ushort)(rc & 0xFFFFu);
  }
  __syncthreads();
  const uint4* s4 = (const uint4*)slab;
  uint4* c4 = ((uint4*)csr) + ((size_t)b<<11);   // 2048 uint4 per bucket
  #pragma unroll
  for(int i=t;i<2048;i+=1024) c4[i] = s4[i];
  if(t<256){
    int node = (b<<8) + t;
    if(node<N) cursor[node] = (int)cnt[t];
    int deg = (int)cnt[t]; if(deg>64) deg=64;
    dv[t] = rsqrtf((float)deg + 1.0f);
  }
  __syncthreads();
  int base = b<<8;
  for(int i=t; i<8192; i+=1024){
    int nl = i>>5;
    int node = base + nl;
    if(node<N){
      float dinv = dv[nl];
      size_t idx = ((size_t)node<<5) + (i&31);
      float4 v = x4[idx];
      uint2 o;
      o.x = (f2bf(v.y*dinv)<<16) | f2bf(v.x*dinv);
      o.y = (f2bf(v.w*dinv)<<16) | f2bf(v.z*dinv);
      xs2[idx] = o;
    }
  }
}

// ---- K3: pure gather-accumulate; one wave per node; guard-free inner loop ----
__global__ void k_agg(const uint4* __restrict__ xs4, const int* __restrict__ cursor,
                      const ushort* __restrict__ csr, int n, uint4* __restrict__ zb4){
  int w = (blockIdx.x*blockDim.x + threadIdx.x)>>6;
  if(w>=n) return;
  int lane = threadIdx.x & 63;
  int grp = lane>>4, li = lane&15;
  int deg = cursor[w]; if(deg>64) deg=64;
  int k0 = w<<6;
  float dd = rsqrtf((float)deg + 1.0f);
  float a0=0.f,a1=0.f,a2=0.f,a3=0.f,a4=0.f,a5=0.f,a6=0.f,a7=0.f;
  if(grp==0){
    uint4 sv = xs4[(w<<4)+li];
    a0=bf_lo(sv.x); a1=bf_hi(sv.x); a2=bf_lo(sv.y); a3=bf_hi(sv.y);
    a4=bf_lo(sv.z); a5=bf_hi(sv.z); a6=bf_lo(sv.w); a7=bf_hi(sv.w);
  }
  for(int kb=0; kb<deg; kb+=16){
    int base = k0 + kb + (grp<<2);
    ushort4 s4 = *(const ushort4*)(csr + base);
    // slots beyond deg hold sentinel index n (zero row) -> no guards
    { uint4 v = xs4[((int)s4.x<<4)+li];
      a0+=bf_lo(v.x); a1+=bf_hi(v.x); a2+=bf_lo(v.y); a3+=bf_hi(v.y);
      a4+=bf_lo(v.z); a5+=bf_hi(v.z); a6+=bf_lo(v.w); a7+=bf_hi(v.w); }
    { uint4 v = xs4[((int)s4.y<<4)+li];
      a0+=bf_lo(v.x); a1+=bf_hi(v.x); a2+=bf_lo(v.y); a3+=bf_hi(v.y);
      a4+=bf_lo(v.z); a5+=bf_hi(v.z); a6+=bf_lo(v.w); a7+=bf_hi(v.w); }
    { uint4 v = xs4[((int)s4.z<<4)+li];
      a0+=bf_lo(v.x); a1+=bf_hi(v.x); a2+=bf_lo(v.y); a3+=bf_hi(v.y);
      a4+=bf_lo(v.z); a5+=bf_hi(v.z); a6+=bf_lo(v.w); a7+=bf_hi(v.w); }
    { uint4 v = xs4[((int)s4.w<<4)+li];
      a0+=bf_lo(v.x); a1+=bf_hi(v.x); a2+=bf_lo(v.y); a3+=bf_hi(v.y);
      a4+=bf_lo(v.z); a5+=bf_hi(v.z); a6+=bf_lo(v.w); a7+=bf_hi(v.w); }
  }
  a0 += __shfl_xor(a0,16,64); a1 += __shfl_xor(a1,16,64);
  a2 += __shfl_xor(a2,16,64); a3 += __shfl_xor(a3,16,64);
  a4 += __shfl_xor(a4,16,64); a5 += __shfl_xor(a5,16,64);
  a6 += __shfl_xor(a6,16,64); a7 += __shfl_xor(a7,16,64);
  a0 += __shfl_xor(a0,32,64); a1 += __shfl_xor(a1,32,64);
  a2 += __shfl_xor(a2,32,64); a3 += __shfl_xor(a3,32,64);
  a4 += __shfl_xor(a4,32,64); a5 += __shfl_xor(a5,32,64);
  a6 += __shfl_xor(a6,32,64); a7 += __shfl_xor(a7,32,64);
  if(grp==0){
    uint4 o;
    o.x = (f2bf(a1*dd)<<16) | f2bf(a0*dd);
    o.y = (f2bf(a3*dd)<<16) | f2bf(a2*dd);
    o.z = (f2bf(a5*dd)<<16) | f2bf(a4*dd);
    o.w = (f2bf(a7*dd)<<16) | f2bf(a6*dd);
    zb4[(w<<4)+li] = o;
  }
}

// ---- K4: MFMA z@W + bias + ReLU + LN + BLOCK-pooled atomics + per-graph
// completion-triggered MLP head (no separate head kernel). ----
__global__ __launch_bounds__(256) void k_gemmln(
    const unsigned* __restrict__ zb, const ushort* __restrict__ Wp,
    const float* __restrict__ bgc, const float* __restrict__ gamma, const float* __restrict__ beta,
    const int* __restrict__ batch, int n,
    float* __restrict__ pool_sum, unsigned* __restrict__ pool_maxu,
    const int* __restrict__ gcnt, const int* __restrict__ gblk,
    unsigned* __restrict__ gdone,
    const float* __restrict__ W1, const float* __restrict__ b1,
    const float* __restrict__ W2, const float* __restrict__ b2,
    const float* __restrict__ W3, const float* __restrict__ b3,
    float* __restrict__ out){
  __shared__ float sred[4][128];
  __shared__ float mred[4][128];
  __shared__ float gl[384];
  __shared__ float hred[2][128];
  __shared__ float h1[128];
  __shared__ float h2[64];
  __shared__ int trig_s;
  int t = threadIdx.x, lane = t & 63, wv = t >> 6;
  int rowBase = blockIdx.x*64;
  int q = lane>>4, nn = lane&15;
  int m = rowBase + wv*16 + nn;
  bf16x8 afr[4];
  if(m < n){
    const char* rp = (const char*)zb + (size_t)m*256;
    #pragma unroll
    for(int kt=0;kt<4;kt++)
      afr[kt] = *(const bf16x8*)(rp + kt*64 + q*16);
  } else {
    #pragma unroll
    for(int kt=0;kt<4;kt++) afr[kt] = (bf16x8){0,0,0,0,0,0,0,0};
  }

  f32x4 acc[8];
  #pragma unroll
  for(int ct=0;ct<8;ct++){
    f32x4 c = {0.f,0.f,0.f,0.f};
    #pragma unroll
    for(int kt=0;kt<4;kt++){
      bf16x8 bfr = *(const bf16x8*)(Wp + ((size_t)(kt*8+ct)*64 + lane)*8);
      c = __builtin_amdgcn_mfma_f32_16x16x32_bf16(afr[kt], bfr, c, 0, 0, 0);
    }
    acc[ct] = c;
  }
  // acc[ct][r] = h_pre[row = rowBase + wv*16 + q*4 + r][col = ct*16 + nn]
  float s[4]={0,0,0,0}, qq[4]={0,0,0,0};
  #pragma unroll
  for(int ct=0;ct<8;ct++){
    float bb = bgc[ct*16+nn];
    #pragma unroll
    for(int r=0;r<4;r++){
      float v = acc[ct][r] + bb;
      v = fmaxf(v, 0.f);
      acc[ct][r] = v;
      s[r] += v; qq[r] += v*v;
    }
  }
  #pragma unroll
  for(int d=1; d<16; d<<=1){
    #pragma unroll
    for(int r=0;r<4;r++){
      s[r]  += __shfl_xor(s[r],  d, 64);
      qq[r] += __shfl_xor(qq[r], d, 64);
    }
  }
  float mu[4], isd[4];
  #pragma unroll
  for(int r=0;r<4;r++){
    mu[r] = s[r]*(1.f/128.f);
    float var = qq[r]*(1.f/128.f) - mu[r]*mu[r];
    isd[r] = rsqrtf(var + EPS);
  }
  #pragma unroll
  for(int ct=0;ct<8;ct++){
    float gm = gamma[ct*16+nn], bt = beta[ct*16+nn];
    #pragma unroll
    for(int r=0;r<4;r++)
      acc[ct][r] = (acc[ct][r]-mu[r])*isd[r]*gm + bt;
  }
  int gbr[4];
  #pragma unroll
  for(int r=0;r<4;r++){
    int gr = rowBase + wv*16 + q*4 + r;
    gbr[r] = (gr < n) ? batch[gr] : -1;
  }
  int b0i = rowBase; if(b0i >= n) b0i = n-1;
  int b63i = rowBase + 63; if(b63i >= n) b63i = n-1;
  int gmin = batch[b0i], gmax = batch[b63i];
  if(gmax < gmin) gmax = gmin;
  for(int g=gmin; g<=gmax; ++g){
    #pragma unroll
    for(int ct=0;ct<8;ct++){
      float ssum = 0.f, smax = -FLT_BIG;
      #pragma unroll
      for(int r=0;r<4;r++){
        if(gbr[r]==g){
          ssum += acc[ct][r];
          smax = fmaxf(smax, acc[ct][r]);
        }
      }
      ssum += __shfl_xor(ssum, 16, 64);
      ssum += __shfl_xor(ssum, 32, 64);
      float o1 = __shfl_xor(smax, 16, 64); smax = fmaxf(smax, o1);
      float o2 = __shfl_xor(smax, 32, 64); smax = fmaxf(smax, o2);
      if(q==0){
        sred[wv][ct*16+nn] = ssum;
        mred[wv][ct*16+nn] = smax;
      }
    }
    __syncthreads();
    if(t < 128){
      float s0 = (sred[0][t]+sred[1][t]) + (sred[2][t]+sred[3][t]);
      float m0 = fmaxf(fmaxf(mred[0][t],mred[1][t]), fmaxf(mred[2][t],mred[3][t]));
      if(s0 != 0.f)    atomicAdd(&pool_sum[g*128 + t], s0);
      if(m0 > -FLT_BIG) atomicMax(&pool_maxu[g*128 + t], fflip(m0));
    }
    __syncthreads();
    // ---- per-graph completion trigger ----
    if(t==0){
      __threadfence();                         // make this block's pool atomics visible
      unsigned old = atomicAdd(&gdone[g], 1u);
      trig_s = (old == (unsigned)(gblk[g]-1));
    }
    __syncthreads();
    if(trig_s){
      // this block is the last contributor to graph g -> run its MLP head.
      int cnt = gcnt[g];
      float rinv = 1.f/(float)((cnt>1)?cnt:1);
      if(t<128){
        // atomic-reads: device-scope coherent regardless of XCD caches
        float sv = atomicAdd(&pool_sum[g*128+t], 0.f);
        gl[t]     = sv*rinv;
        gl[128+t] = sv;
        unsigned mu_ = atomicOr(&pool_maxu[g*128+t], 0u);
        gl[256+t] = (cnt>0) ? funflip(mu_) : 0.f;
      }
      __syncthreads();
      int j = t & 127, kh = t >> 7;
      float p = 0.f;
      for(int k=kh*192; k<kh*192+192; k++) p += gl[k]*W1[k*128+j];
      hred[kh][j] = p;
      __syncthreads();
      if(t<128) h1[t] = fmaxf(hred[0][t]+hred[1][t]+b1[t], 0.f);
      __syncthreads();
      if(t<64){
        float a = b2[t];
        for(int k=0;k<128;k++) a += h1[k]*W2[k*64+t];
        h2[t] = fmaxf(a, 0.f);
      }
      __syncthreads();
      if(t<10){
        float a = b3[t];
        for(int k=0;k<64;k++) a += h2[k]*W3[k*10+t];
        out[g*10+t] = a;
      }
    }
    __syncthreads();
  }
}

extern "C" void kernel_launch(void* const* d_in, const int* in_sizes, int n_in,
                              void* d_out, int out_size, void* d_ws, size_t ws_size,
                              hipStream_t stream){
  const float* x     = (const float*)d_in[0];
  const int*   ei    = (const int*)d_in[1];
  const int*   batch = (const int*)d_in[2];
  const float* Wg    = (const float*)d_in[4];
  const float* bg    = (const float*)d_in[5];
  const float* gamma = (const float*)d_in[6];
  const float* beta  = (const float*)d_in[7];
  const float* W1    = (const float*)d_in[8];
  const float* b1    = (const float*)d_in[9];
  const float* W2    = (const float*)d_in[10];
  const float* b2    = (const float*)d_in[11];
  const float* W3    = (const float*)d_in[12];
  const float* b3    = (const float*)d_in[13];
  float* out = (float*)d_out;

  int N = in_sizes[0]/128;
  int E = in_sizes[1]/2;
  const int G = 64;
  const int* src = ei;
  const int* dst = ei + E;
  int NB = (N+255)>>8;

  char* p = (char*)d_ws;
  auto alloc=[&](size_t bytes)->char*{ char* r=p; p += (bytes+255)&~(size_t)255; return r; };
  // contiguous zero-region: psum | pmaxu | gcur | gdone  (single memsetAsync)
  size_t zr_bytes = (size_t)G*128*4*2 + 1024 + 1024;
  char*     zr      = alloc(zr_bytes);
  float*    psum    = (float*)zr;
  unsigned* pmaxu   = (unsigned*)(zr + (size_t)G*128*4);
  unsigned* gcur    = (unsigned*)(zr + (size_t)G*128*4*2);
  unsigned* gdone   = (unsigned*)(zr + (size_t)G*128*4*2 + 1024);
  int*      cursor  = (int*)     alloc((size_t)N*4);
  ushort*   csr     = (ushort*)  alloc((size_t)NB*16384*2);
  unsigned* zb      = (unsigned*)alloc((size_t)N*64*4);
  unsigned* xs      = (unsigned*)alloc((size_t)(N+1)*64*4);  // +1 sentinel zero row
  ushort*   Wp      = (ushort*)  alloc(2048*8*2);
  int*      gcnt    = (int*)     alloc((size_t)G*4);
  int*      gblk    = (int*)     alloc((size_t)G*4);
  unsigned* dstream = (unsigned*)alloc((size_t)NB*8192*4);

  hipMemsetAsync(zr, 0, zr_bytes, stream);
  int bb = (E+2047)/2048;
  k_bucketize<<<bb,256,0,stream>>>(src,dst,E,NB,gcur,dstream,Wg,Wp,batch,N,gcnt,gblk,G);
  k_csrscale<<<NB,1024,0,stream>>>(dstream,gcur,N,csr,cursor,(const float4*)x,(uint2*)xs);
  int ab = (int)(((size_t)N*64 + 255)/256);
  k_agg<<<ab,256,0,stream>>>((const uint4*)xs,cursor,csr,N,(uint4*)zb);
  k_gemmln<<<(N+63)/64,256,0,stream>>>(zb,Wp,bg,gamma,beta,batch,N,psum,pmaxu,
                                       gcnt,gblk,gdone,W1,b1,W2,b2,W3,b3,out);
}

// Round 11
// 156.723 us; speedup vs baseline: 1.0966x; 1.0966x over previous
//
#include <hip/hip_runtime.h>
#include <math.h>

#define EPS 1e-5f
#define FLT_BIG 3.402823466e38f

typedef __attribute__((ext_vector_type(8))) short bf16x8;
typedef __attribute__((ext_vector_type(4))) float f32x4;

__device__ __forceinline__ unsigned fflip(float f){
  int i = __float_as_int(f);
  return (unsigned)(i ^ ((i>>31) | 0x80000000));
}
__device__ __forceinline__ float funflip(unsigned u){
  int i = (u & 0x80000000u) ? (int)(u ^ 0x80000000u) : (int)(~u);
  return __int_as_float(i);
}
__device__ __forceinline__ unsigned f2bf(float f){
  unsigned u = __float_as_uint(f);
  return (u + 0x7FFFu + ((u>>16)&1u)) >> 16;
}
__device__ __forceinline__ float bf_lo(unsigned v){ return __uint_as_float(v<<16); }
__device__ __forceinline__ float bf_hi(unsigned v){ return __uint_as_float(v & 0xFFFF0000u); }

__device__ __forceinline__ int lbound(const int* __restrict__ a, int n, int key){
  int lo=0, hi=n;
  while(lo<hi){ int mid=(lo+hi)>>1; if(a[mid]<key) lo=mid+1; else hi=mid; }
  return lo;
}

// ---- K1: multisplit bucketize (per-wave hist) + folded init side-work ----
// Record = (b<<24)|(dlow<<16)|src. Tile = 2048 edges/block.
// Blocks 0-7 additionally pack W into B-frag order; block 8 computes gcnt.
__global__ __launch_bounds__(256) void k_bucketize(
    const int* __restrict__ src, const int* __restrict__ dst, int E, int NB,
    unsigned* __restrict__ gcur, unsigned* __restrict__ dstream,
    const float* __restrict__ Wg, ushort* __restrict__ Wp,
    const int* __restrict__ batch, int N, int* __restrict__ gcnt, int G){
  __shared__ unsigned whist[4][160];   // per-wave counts, then per-wave excl bases
  __shared__ unsigned hist[160];       // per-bucket totals
  __shared__ unsigned excl[160];
  __shared__ unsigned base[160];
  __shared__ unsigned wsum[4];
  __shared__ unsigned lsorted[2048];
  int t = threadIdx.x, bid = blockIdx.x;
  int wid = t>>6, lane = t&63;

  // ---- folded init side-work (independent of edge path) ----
  if(bid < 8){
    int i = bid*256 + t;                 // 0..2047
    int tile = i>>6, l = i&63;
    int kt = tile>>3, ct = tile&7;
    int q = l>>4, nn = l&15;
    ushort w8[8];
    #pragma unroll
    for(int j=0;j<8;j++)
      w8[j] = (ushort)f2bf(Wg[(kt*32 + q*8 + j)*128 + ct*16 + nn]);
    ushort* dstp = Wp + (size_t)i*8;
    #pragma unroll
    for(int j=0;j<8;j++) dstp[j] = w8[j];
  } else if(bid == 8){
    if(t < G){
      int s = lbound(batch,N,t), e = lbound(batch,N,t+1);
      gcnt[t] = e - s;
    }
  }

  // ---- edge path ----
  int e0 = bid*2048 + t*8;
  unsigned rec[8]; int bk[8]; unsigned rr[8];
  #pragma unroll
  for(int j=0;j<8;j++) bk[j] = -1;
  if(e0+7 < E){
    int4 s0 = *(const int4*)(src+e0), s1 = *(const int4*)(src+e0+4);
    int4 d0 = *(const int4*)(dst+e0), d1 = *(const int4*)(dst+e0+4);
    int ss[8] = {s0.x,s0.y,s0.z,s0.w,s1.x,s1.y,s1.z,s1.w};
    int dd[8] = {d0.x,d0.y,d0.z,d0.w,d1.x,d1.y,d1.z,d1.w};
    #pragma unroll
    for(int j=0;j<8;j++){
      bk[j] = dd[j]>>8;
      rec[j] = ((unsigned)bk[j]<<24) | ((unsigned)(dd[j]&255)<<16) | (unsigned)ss[j];
    }
  } else {
    #pragma unroll
    for(int j=0;j<8;j++){
      int ee = e0+j;
      if(ee<E){
        int s = src[ee], d = dst[ee];
        bk[j] = d>>8;
        rec[j] = ((unsigned)bk[j]<<24) | ((unsigned)(d&255)<<16) | (unsigned)s;
      }
    }
  }
  for(int i=t;i<NB;i+=256){
    whist[0][i]=0u; whist[1][i]=0u; whist[2][i]=0u; whist[3][i]=0u;
  }
  __syncthreads();
  #pragma unroll
  for(int j=0;j<8;j++)
    if(bk[j]>=0) rr[j] = atomicAdd(&whist[wid][bk[j]],1u);
  __syncthreads();
  // per-bucket totals + per-wave exclusive bases
  unsigned hv = 0u;
  if(t<NB){
    unsigned h0=whist[0][t], h1=whist[1][t], h2=whist[2][t], h3=whist[3][t];
    hv = h0+h1+h2+h3;
    hist[t] = hv;
    whist[0][t]=0u; whist[1][t]=h0; whist[2][t]=h0+h1; whist[3][t]=h0+h1+h2;
  }
  // exclusive scan of hv via wave shfl scans + 1 barrier
  unsigned v = hv;
  #pragma unroll
  for(int d=1; d<64; d<<=1){
    unsigned o = __shfl_up(v, d, 64);
    if(lane >= d) v += o;
  }
  if(lane==63) wsum[wid] = v;
  __syncthreads();
  {
    unsigned pre = 0;
    if(wid>0) pre += wsum[0];
    if(wid>1) pre += wsum[1];
    if(wid>2) pre += wsum[2];
    if(t<NB) excl[t] = v + pre - hv;
  }
  if(t<NB){
    int ridx = t + bid; while(ridx>=NB) ridx-=NB;  // stagger global atomics
    base[ridx] = atomicAdd(&gcur[ridx], hist[ridx]);
  }
  __syncthreads();
  #pragma unroll
  for(int j=0;j<8;j++)
    if(bk[j]>=0) lsorted[excl[bk[j]] + whist[wid][bk[j]] + rr[j]] = rec[j];
  __syncthreads();
  int vc = E - bid*2048; if(vc>2048) vc=2048;
  #pragma unroll
  for(int j=0;j<8;j++){
    int k = j*256 + t;
    if(k<vc){
      unsigned rc = lsorted[k];
      unsigned bb = rc>>24;
      unsigned pos = base[bb] + (unsigned)k - excl[bb];
      if(pos < 8192u) dstream[((size_t)bb<<13) + pos] = rc;
    }
  }
}

// ---- K2: per-bucket CSR build in LDS (sentinel-padded) + writeout + fused dinv-scale ----
// Slab slots beyond a node's degree hold sentinel index N (a zero row in xs),
// so k_agg needs no tail guards.
__global__ __launch_bounds__(1024) void k_csrscale(
    const unsigned* __restrict__ dstream, const unsigned* __restrict__ gcur,
    int N, ushort* __restrict__ csr, int* __restrict__ cursor,
    const float4* __restrict__ x4, uint2* __restrict__ xs2){
  __shared__ unsigned cnt[256];
  __shared__ float dv[256];
  __shared__ ushort slab[16384];       // 256 nodes x 64 slots = 2048 uint4
  int b = blockIdx.x, t = threadIdx.x;
  if(t<256) cnt[t]=0u;
  {
    unsigned sv = ((unsigned)N<<16) | (unsigned)N;   // sentinel bf pair
    uint4 fillv = make_uint4(sv,sv,sv,sv);
    #pragma unroll
    for(int i=t;i<2048;i+=1024) ((uint4*)slab)[i] = fillv;  // ALL 32768 B
  }
  // zero row N of xs (sentinel target), once
  if(b==0 && t<16) ((uint4*)(xs2 + ((size_t)N<<5)))[t] = make_uint4(0,0,0,0);
  __syncthreads();
  int nb = (int)gcur[b]; if(nb>8192) nb=8192;
  const unsigned* sp = dstream + ((size_t)b<<13);
  for(int i=t;i<nb;i+=1024){
    unsigned rc = sp[i];
    int dl = (rc>>16)&255;
    unsigned p = atomicAdd(&cnt[dl],1u);
    if(p<64u) slab[(dl<<6)+(int)p] = (ushort)(rc & 0xFFFFu);
  }
  __syncthreads();
  const uint4* s4 = (const uint4*)slab;
  uint4* c4 = ((uint4*)csr) + ((size_t)b<<11);   // 2048 uint4 per bucket
  #pragma unroll
  for(int i=t;i<2048;i+=1024) c4[i] = s4[i];
  if(t<256){
    int node = (b<<8) + t;
    if(node<N) cursor[node] = (int)cnt[t];
    int deg = (int)cnt[t]; if(deg>64) deg=64;
    dv[t] = rsqrtf((float)deg + 1.0f);
  }
  __syncthreads();
  int base = b<<8;
  for(int i=t; i<8192; i+=1024){
    int nl = i>>5;
    int node = base + nl;
    if(node<N){
      float dinv = dv[nl];
      size_t idx = ((size_t)node<<5) + (i&31);
      float4 v = x4[idx];
      uint2 o;
      o.x = (f2bf(v.y*dinv)<<16) | f2bf(v.x*dinv);
      o.y = (f2bf(v.w*dinv)<<16) | f2bf(v.z*dinv);
      xs2[idx] = o;
    }
  }
}

// ---- K3: pure gather-accumulate; one wave per node; guard-free inner loop ----
__global__ void k_agg(const uint4* __restrict__ xs4, const int* __restrict__ cursor,
                      const ushort* __restrict__ csr, int n, uint4* __restrict__ zb4){
  int w = (blockIdx.x*blockDim.x + threadIdx.x)>>6;
  if(w>=n) return;
  int lane = threadIdx.x & 63;
  int grp = lane>>4, li = lane&15;
  int deg = cursor[w]; if(deg>64) deg=64;
  int k0 = w<<6;
  float dd = rsqrtf((float)deg + 1.0f);
  float a0=0.f,a1=0.f,a2=0.f,a3=0.f,a4=0.f,a5=0.f,a6=0.f,a7=0.f;
  if(grp==0){
    uint4 sv = xs4[(w<<4)+li];
    a0=bf_lo(sv.x); a1=bf_hi(sv.x); a2=bf_lo(sv.y); a3=bf_hi(sv.y);
    a4=bf_lo(sv.z); a5=bf_hi(sv.z); a6=bf_lo(sv.w); a7=bf_hi(sv.w);
  }
  for(int kb=0; kb<deg; kb+=16){
    int base = k0 + kb + (grp<<2);
    ushort4 s4 = *(const ushort4*)(csr + base);
    // slots beyond deg hold sentinel index n (zero row) -> no guards
    { uint4 v = xs4[((int)s4.x<<4)+li];
      a0+=bf_lo(v.x); a1+=bf_hi(v.x); a2+=bf_lo(v.y); a3+=bf_hi(v.y);
      a4+=bf_lo(v.z); a5+=bf_hi(v.z); a6+=bf_lo(v.w); a7+=bf_hi(v.w); }
    { uint4 v = xs4[((int)s4.y<<4)+li];
      a0+=bf_lo(v.x); a1+=bf_hi(v.x); a2+=bf_lo(v.y); a3+=bf_hi(v.y);
      a4+=bf_lo(v.z); a5+=bf_hi(v.z); a6+=bf_lo(v.w); a7+=bf_hi(v.w); }
    { uint4 v = xs4[((int)s4.z<<4)+li];
      a0+=bf_lo(v.x); a1+=bf_hi(v.x); a2+=bf_lo(v.y); a3+=bf_hi(v.y);
      a4+=bf_lo(v.z); a5+=bf_hi(v.z); a6+=bf_lo(v.w); a7+=bf_hi(v.w); }
    { uint4 v = xs4[((int)s4.w<<4)+li];
      a0+=bf_lo(v.x); a1+=bf_hi(v.x); a2+=bf_lo(v.y); a3+=bf_hi(v.y);
      a4+=bf_lo(v.z); a5+=bf_hi(v.z); a6+=bf_lo(v.w); a7+=bf_hi(v.w); }
  }
  a0 += __shfl_xor(a0,16,64); a1 += __shfl_xor(a1,16,64);
  a2 += __shfl_xor(a2,16,64); a3 += __shfl_xor(a3,16,64);
  a4 += __shfl_xor(a4,16,64); a5 += __shfl_xor(a5,16,64);
  a6 += __shfl_xor(a6,16,64); a7 += __shfl_xor(a7,16,64);
  a0 += __shfl_xor(a0,32,64); a1 += __shfl_xor(a1,32,64);
  a2 += __shfl_xor(a2,32,64); a3 += __shfl_xor(a3,32,64);
  a4 += __shfl_xor(a4,32,64); a5 += __shfl_xor(a5,32,64);
  a6 += __shfl_xor(a6,32,64); a7 += __shfl_xor(a7,32,64);
  if(grp==0){
    uint4 o;
    o.x = (f2bf(a1*dd)<<16) | f2bf(a0*dd);
    o.y = (f2bf(a3*dd)<<16) | f2bf(a2*dd);
    o.z = (f2bf(a5*dd)<<16) | f2bf(a4*dd);
    o.w = (f2bf(a7*dd)<<16) | f2bf(a6*dd);
    zb4[(w<<4)+li] = o;
  }
}

// ---- K4: MFMA z@W + bias + ReLU + LN + BLOCK-pooled atomics ----
__global__ __launch_bounds__(256) void k_gemmln(
    const unsigned* __restrict__ zb, const ushort* __restrict__ Wp,
    const float* __restrict__ bgc, const float* __restrict__ gamma, const float* __restrict__ beta,
    const int* __restrict__ batch, int n,
    float* __restrict__ pool_sum, unsigned* __restrict__ pool_maxu){
  __shared__ float sred[4][128];
  __shared__ float mred[4][128];
  int t = threadIdx.x, lane = t & 63, wv = t >> 6;
  int rowBase = blockIdx.x*64;
  int q = lane>>4, nn = lane&15;
  int m = rowBase + wv*16 + nn;
  bf16x8 afr[4];
  if(m < n){
    const char* rp = (const char*)zb + (size_t)m*256;
    #pragma unroll
    for(int kt=0;kt<4;kt++)
      afr[kt] = *(const bf16x8*)(rp + kt*64 + q*16);
  } else {
    #pragma unroll
    for(int kt=0;kt<4;kt++) afr[kt] = (bf16x8){0,0,0,0,0,0,0,0};
  }

  f32x4 acc[8];
  #pragma unroll
  for(int ct=0;ct<8;ct++){
    f32x4 c = {0.f,0.f,0.f,0.f};
    #pragma unroll
    for(int kt=0;kt<4;kt++){
      bf16x8 bfr = *(const bf16x8*)(Wp + ((size_t)(kt*8+ct)*64 + lane)*8);
      c = __builtin_amdgcn_mfma_f32_16x16x32_bf16(afr[kt], bfr, c, 0, 0, 0);
    }
    acc[ct] = c;
  }
  // acc[ct][r] = h_pre[row = rowBase + wv*16 + q*4 + r][col = ct*16 + nn]
  float s[4]={0,0,0,0}, qq[4]={0,0,0,0};
  #pragma unroll
  for(int ct=0;ct<8;ct++){
    float bb = bgc[ct*16+nn];
    #pragma unroll
    for(int r=0;r<4;r++){
      float v = acc[ct][r] + bb;
      v = fmaxf(v, 0.f);
      acc[ct][r] = v;
      s[r] += v; qq[r] += v*v;
    }
  }
  #pragma unroll
  for(int d=1; d<16; d<<=1){
    #pragma unroll
    for(int r=0;r<4;r++){
      s[r]  += __shfl_xor(s[r],  d, 64);
      qq[r] += __shfl_xor(qq[r], d, 64);
    }
  }
  float mu[4], isd[4];
  #pragma unroll
  for(int r=0;r<4;r++){
    mu[r] = s[r]*(1.f/128.f);
    float var = qq[r]*(1.f/128.f) - mu[r]*mu[r];
    isd[r] = rsqrtf(var + EPS);
  }
  #pragma unroll
  for(int ct=0;ct<8;ct++){
    float gm = gamma[ct*16+nn], bt = beta[ct*16+nn];
    #pragma unroll
    for(int r=0;r<4;r++)
      acc[ct][r] = (acc[ct][r]-mu[r])*isd[r]*gm + bt;
  }
  int gbr[4];
  #pragma unroll
  for(int r=0;r<4;r++){
    int gr = rowBase + wv*16 + q*4 + r;
    gbr[r] = (gr < n) ? batch[gr] : -1;
  }
  int b0i = rowBase; if(b0i >= n) b0i = n-1;
  int b63i = rowBase + 63; if(b63i >= n) b63i = n-1;
  int gmin = batch[b0i], gmax = batch[b63i];
  if(gmax < gmin) gmax = gmin;
  for(int g=gmin; g<=gmax; ++g){
    #pragma unroll
    for(int ct=0;ct<8;ct++){
      float ssum = 0.f, smax = -FLT_BIG;
      #pragma unroll
      for(int r=0;r<4;r++){
        if(gbr[r]==g){
          ssum += acc[ct][r];
          smax = fmaxf(smax, acc[ct][r]);
        }
      }
      ssum += __shfl_xor(ssum, 16, 64);
      ssum += __shfl_xor(ssum, 32, 64);
      float o1 = __shfl_xor(smax, 16, 64); smax = fmaxf(smax, o1);
      float o2 = __shfl_xor(smax, 32, 64); smax = fmaxf(smax, o2);
      if(q==0){
        sred[wv][ct*16+nn] = ssum;
        mred[wv][ct*16+nn] = smax;
      }
    }
    __syncthreads();
    if(t < 128){
      float s0 = (sred[0][t]+sred[1][t]) + (sred[2][t]+sred[3][t]);
      float m0 = fmaxf(fmaxf(mred[0][t],mred[1][t]), fmaxf(mred[2][t],mred[3][t]));
      if(s0 != 0.f)    atomicAdd(&pool_sum[g*128 + t], s0);
      if(m0 > -FLT_BIG) atomicMax(&pool_maxu[g*128 + t], fflip(m0));
    }
    __syncthreads();
  }
}

// ---- K5: MLP head, one block per graph, 512 threads, 4-way k-split ----
__global__ __launch_bounds__(512) void k_head(
    const float* __restrict__ pool_sum, const unsigned* __restrict__ pool_maxu,
    const int* __restrict__ gcnt,
    const float* __restrict__ W1, const float* __restrict__ b1,
    const float* __restrict__ W2, const float* __restrict__ b2,
    const float* __restrict__ W3, const float* __restrict__ b3,
    float* __restrict__ out){
  int g = blockIdx.x, t = threadIdx.x;
  __shared__ float red[4][128];
  __shared__ float gl[384];
  __shared__ float h1[128];
  __shared__ float h2[64];
  int cnt = gcnt[g];
  if(t<384){
    int j = t & 127;
    if(t<128){
      gl[t] = pool_sum[g*128+j] / (float)((cnt>1)?cnt:1);
    } else if(t<256){
      gl[t] = pool_sum[g*128+j];
    } else {
      float m = funflip(pool_maxu[g*128+j]);
      gl[t] = (cnt>0) ? m : 0.f;
    }
  }
  __syncthreads();
  int j = t & 127, kh = t >> 7;
  float p=0.f;
  for(int k=kh*96; k<kh*96+96; k++) p += gl[k]*W1[k*128+j];
  red[kh][j]=p;
  __syncthreads();
  if(t<128){
    float v = red[0][t]+red[1][t]+red[2][t]+red[3][t]+b1[t];
    h1[t]=fmaxf(v,0.f);
  }
  __syncthreads();
  if(t<64){
    float a=b2[t];
    for(int k=0;k<128;k++) a += h1[k]*W2[k*64+t];
    h2[t]=fmaxf(a,0.f);
  }
  __syncthreads();
  if(t<10){
    float a=b3[t];
    for(int k=0;k<64;k++) a += h2[k]*W3[k*10+t];
    out[g*10+t]=a;
  }
}

extern "C" void kernel_launch(void* const* d_in, const int* in_sizes, int n_in,
                              void* d_out, int out_size, void* d_ws, size_t ws_size,
                              hipStream_t stream){
  const float* x     = (const float*)d_in[0];
  const int*   ei    = (const int*)d_in[1];
  const int*   batch = (const int*)d_in[2];
  const float* Wg    = (const float*)d_in[4];
  const float* bg    = (const float*)d_in[5];
  const float* gamma = (const float*)d_in[6];
  const float* beta  = (const float*)d_in[7];
  const float* W1    = (const float*)d_in[8];
  const float* b1    = (const float*)d_in[9];
  const float* W2    = (const float*)d_in[10];
  const float* b2    = (const float*)d_in[11];
  const float* W3    = (const float*)d_in[12];
  const float* b3    = (const float*)d_in[13];
  float* out = (float*)d_out;

  int N = in_sizes[0]/128;
  int E = in_sizes[1]/2;
  const int G = 64;
  const int* src = ei;
  const int* dst = ei + E;
  int NB = (N+255)>>8;

  char* p = (char*)d_ws;
  auto alloc=[&](size_t bytes)->char*{ char* r=p; p += (bytes+255)&~(size_t)255; return r; };
  // contiguous zero-region: psum | pmaxu | gcur  (single memsetAsync)
  size_t zr_bytes = (size_t)G*128*4 + (size_t)G*128*4 + 1024;
  char*     zr      = alloc(zr_bytes);
  float*    psum    = (float*)zr;
  unsigned* pmaxu   = (unsigned*)(zr + (size_t)G*128*4);
  unsigned* gcur    = (unsigned*)(zr + (size_t)G*128*4*2);
  int*      cursor  = (int*)     alloc((size_t)N*4);
  ushort*   csr     = (ushort*)  alloc((size_t)NB*16384*2);
  unsigned* zb      = (unsigned*)alloc((size_t)N*64*4);
  unsigned* xs      = (unsigned*)alloc((size_t)(N+1)*64*4);  // +1 sentinel zero row
  ushort*   Wp      = (ushort*)  alloc(2048*8*2);
  int*      gcnt    = (int*)     alloc((size_t)G*4);
  unsigned* dstream = (unsigned*)alloc((size_t)NB*8192*4);

  hipMemsetAsync(zr, 0, zr_bytes, stream);
  int bb = (E+2047)/2048;
  k_bucketize<<<bb,256,0,stream>>>(src,dst,E,NB,gcur,dstream,Wg,Wp,batch,N,gcnt,G);
  k_csrscale<<<NB,1024,0,stream>>>(dstream,gcur,N,csr,cursor,(const float4*)x,(uint2*)xs);
  int ab = (int)(((size_t)N*64 + 255)/256);
  k_agg<<<ab,256,0,stream>>>((const uint4*)xs,cursor,csr,N,(uint4*)zb);
  k_gemmln<<<(N+63)/64,256,0,stream>>>(zb,Wp,bg,gamma,beta,batch,N,psum,pmaxu);
  k_head<<<G,512,0,stream>>>(psum,pmaxu,gcnt,W1,b1,W2,b2,W3,b3,out);
}